// Round 1
// baseline (242.844 us; speedup 1.0000x reference)
//
#include <hip/hip_runtime.h>
#include <math.h>

#define NN 5000
#define NBINS 50
#define BINSZ 100
#define KNN 16
#define BPAD 104          // padded M row length (halves); 208 B stride, 16B aligned
#define MROWS 112         // padded row count in conv phase
#define NB 20             // nodes per block in MLP phases (5 groups x 4)
#define NBLK 250

typedef _Float16 half8 __attribute__((ext_vector_type(8)));

__device__ __forceinline__ float lrelu(float x){ return x >= 0.f ? x : 0.01f*x; }

// LDS union across phases (max ~60.2 KB -> 2 blocks/CU capacity; we need 1)
union SharedU {
    struct {                                    // phase 0: nn1 + LSH  (54.2 KB)
        float sW[8000];
        float bufX[12 * NB];
        float bufA[125 * NB];
        float bufB[125 * NB];
        float sCB[300];
    } p0;
    struct {                                    // phase 1: scatter    (20.1 KB)
        int sBI[NN];
        int s_lt[10];
        int s_eq[10];
    } p1;
    struct {                                    // phase 2: build+conv (57.1 KB)
        _Float16 M[MROWS * BPAD];
        float s_h[BINSZ * 12];
        int   s_nodes[BINSZ];
        float s_dis[BINSZ];
        float s_w[12 * 32];
        union {
            unsigned s_tv[200 * KNN];           // top-k keys (build)
            struct { float hWd[32 * BPAD]; float gcn[32 * BPAD]; } c;  // conv
        } u;
    } p2;
    struct {                                    // phase 3: nn23       (60.2 KB)
        float sW[8000];
        float sAG[32 * NB];
        float sGC[32 * NB];
        float bufC[38 * NB];
        float bufA[125 * NB];
        float bufB[125 * NB];
    } p3;
};

// device-scope grid barrier; bar[] zeroed by init_kernel each launch.
// All 250 blocks are co-resident (250 <= 256 CUs, 60.2KB LDS, 10 waves) so
// spin-wait cannot deadlock on an exclusively-held chip.
__device__ __forceinline__ void gbar(int* bar, int idx) {
    __syncthreads();
    if (threadIdx.x == 0) {
        __threadfence();   // release: flush per-XCD-visible writes to coherence point
        __hip_atomic_fetch_add(bar + idx, 1, __ATOMIC_RELEASE, __HIP_MEMORY_SCOPE_AGENT);
        while (__hip_atomic_load(bar + idx, __ATOMIC_ACQUIRE, __HIP_MEMORY_SCOPE_AGENT) < NBLK)
            __builtin_amdgcn_s_sleep(1);
        __threadfence();   // acquire: invalidate caches before post-barrier reads
    }
    __syncthreads();
}

__global__ void init_kernel(int* bar) {
    if (threadIdx.x < 8) bar[threadIdx.x] = 0;
}

__global__ __launch_bounds__(640) void fused_kernel(
    const float* __restrict__ x,
    const float4* __restrict__ ygen_id4, const float4* __restrict__ ygen4,
    const float* __restrict__ cb,
    const float* __restrict__ W1, const float* __restrict__ b1,
    const float* __restrict__ W2, const float* __restrict__ b2,
    const float* __restrict__ W3, const float* __restrict__ b3,
    const float* __restrict__ gcn_W, const float* __restrict__ gcn_b,
    const float* __restrict__ Wrel, const float* __restrict__ brel,
    const float* __restrict__ Wroot,
    const float* __restrict__ A1, const float* __restrict__ ab1,
    const float* __restrict__ A2, const float* __restrict__ ab2,
    const float* __restrict__ A3, const float* __restrict__ ab3,
    const float* __restrict__ B1, const float* __restrict__ bb1,
    const float* __restrict__ B2, const float* __restrict__ bb2,
    const float* __restrict__ B3, const float* __restrict__ bb3,
    float* __restrict__ h, float* __restrict__ gcn_n, float* __restrict__ agg_n,
    int* __restrict__ bin_idx, int* __restrict__ order, int* __restrict__ bar,
    float* __restrict__ out_ids, float* __restrict__ out_p4,
    float4* __restrict__ out4)
{
    __shared__ SharedU S;
    int tid = threadIdx.x;

    // ================= phase 0: fused MLP1 + LSH bin (all 250 blocks) =============
    {
        int n0 = blockIdx.x * NB;
        int g = tid >> 7, j = tid & 127;
        float acc[4];
        float4 r0, r1; float rt = 0.f;

        if (tid < 60) {
            float4 v = ((const float4*)(x + n0 * 12))[tid];
            int e = tid * 4;
            S.p0.bufX[(e % 12) * NB + (e / 12)] = v.x;
            S.p0.bufX[((e + 1) % 12) * NB + ((e + 1) / 12)] = v.y;
            S.p0.bufX[((e + 2) % 12) * NB + ((e + 2) / 12)] = v.z;
            S.p0.bufX[((e + 3) % 12) * NB + ((e + 3) / 12)] = v.w;
        }
        if (tid < 300) { int k = tid / 25, c = tid - k * 25; S.p0.sCB[tid] = cb[k * 100 + c]; }
        if (tid < 375) ((float4*)S.p0.sW)[tid] = ((const float4*)W1)[tid];
        __syncthreads();

        // L1: 12 -> 125
        if (j < 125) {
            float bj = b1[j];
            acc[0] = bj; acc[1] = bj; acc[2] = bj; acc[3] = bj;
            #pragma unroll
            for (int k = 0; k < 12; ++k) {
                float w = S.p0.sW[k * 125 + j];
                float4 a = *(const float4*)&S.p0.bufX[k * NB + g * 4];
                acc[0] += a.x * w; acc[1] += a.y * w; acc[2] += a.z * w; acc[3] += a.w * w;
            }
            #pragma unroll
            for (int n = 0; n < 4; ++n) S.p0.bufA[j * NB + g * 4 + n] = lrelu(acc[n]);
        }
        r0 = (tid < 1000) ? ((const float4*)W2)[tid] : make_float4(0.f,0.f,0.f,0.f);
        r1 = (tid < 360)  ? ((const float4*)W2)[tid + 640] : make_float4(0.f,0.f,0.f,0.f);
        __syncthreads();
        if (tid < 1000) ((float4*)S.p0.sW)[tid] = r0;
        if (tid < 360)  ((float4*)S.p0.sW)[tid + 640] = r1;
        __syncthreads();

        // L2: 125 -> 125, chunked dbuf
        if (j < 125) { float bj = b2[j]; acc[0] = bj; acc[1] = bj; acc[2] = bj; acc[3] = bj; }
        for (int c = 0; c < 4; ++c) {
            if (c < 3) {
                int base = (c + 1) * 1000, nf4 = (c + 1 < 3) ? 1000 : 906;
                r0 = (tid < nf4) ? ((const float4*)W2)[base + tid] : make_float4(0.f,0.f,0.f,0.f);
                r1 = (tid + 640 < nf4) ? ((const float4*)W2)[base + tid + 640] : make_float4(0.f,0.f,0.f,0.f);
                if (c + 1 == 3 && tid == 0) rt = W2[15624];
            }
            int nk = (c < 3) ? 32 : 29;
            const float* wbuf = S.p0.sW + (c & 1) * 4000;
            if (j < 125) {
                const float* arow = &S.p0.bufA[(c * 32) * NB + g * 4];
                for (int k = 0; k < nk; ++k) {
                    float w = wbuf[k * 125 + j];
                    float4 a = *(const float4*)&arow[k * NB];
                    acc[0] += a.x * w; acc[1] += a.y * w; acc[2] += a.z * w; acc[3] += a.w * w;
                }
            }
            if (c < 3) {
                float* dst = S.p0.sW + ((c + 1) & 1) * 4000;
                int nf4 = (c + 1 < 3) ? 1000 : 906;
                if (tid < nf4) ((float4*)dst)[tid] = r0;
                if (tid + 640 < nf4) ((float4*)dst)[tid + 640] = r1;
                if (c + 1 == 3 && tid == 0) dst[3624] = rt;
                __syncthreads();
            }
        }
        if (j < 125) {
            #pragma unroll
            for (int n = 0; n < 4; ++n) S.p0.bufB[j * NB + g * 4 + n] = lrelu(acc[n]);
        }
        __syncthreads();
        if (tid < 375) ((float4*)S.p0.sW)[tid] = ((const float4*)W3)[tid];
        __syncthreads();

        // L3: 125 -> 12, 4-way k-split
        if (j < 48) {
            int jj = j % 12, s = j / 12;
            int k0 = s * 32, nk = (s < 3) ? 32 : 29;
            float ps[4] = {0.f, 0.f, 0.f, 0.f};
            for (int k = 0; k < nk; ++k) {
                float w = S.p0.sW[(k0 + k) * 12 + jj];
                float4 a = *(const float4*)&S.p0.bufB[(k0 + k) * NB + g * 4];
                ps[0] += a.x * w; ps[1] += a.y * w; ps[2] += a.z * w; ps[3] += a.w * w;
            }
            #pragma unroll
            for (int n = 0; n < 4; ++n) S.p0.bufA[(s * 12 + jj) * NB + g * 4 + n] = ps[n];
        }
        __syncthreads();
        if (tid < 240) {
            int jj = tid / 20, n = tid % 20;
            float v = S.p0.bufA[jj * NB + n] + S.p0.bufA[(12 + jj) * NB + n]
                    + S.p0.bufA[(24 + jj) * NB + n] + S.p0.bufA[(36 + jj) * NB + n] + b3[jj];
            h[(n0 + n) * 12 + jj] = v;
            S.p0.bufB[jj * NB + n] = v;
        }
        __syncthreads();

        // LSH bin (argmax over [mul,-mul], first max wins)
        if (tid < NB) {
            int n = tid;
            float hv[12];
            #pragma unroll
            for (int k = 0; k < 12; ++k) hv[k] = S.p0.bufB[k * NB + n];
            float best = -INFINITY; int bi = 0;
            for (int c = 0; c < 25; ++c) {
                float m = 0.f;
                #pragma unroll
                for (int k = 0; k < 12; ++k) m += hv[k] * S.p0.sCB[k * 25 + c];
                if (m > best) { best = m; bi = c; }
            }
            for (int c = 0; c < 25; ++c) {
                float m = 0.f;
                #pragma unroll
                for (int k = 0; k < 12; ++k) m += hv[k] * S.p0.sCB[k * 25 + c];
                if (-m > best) { best = -m; bi = c + 25; }
            }
            bin_idx[n0 + n] = bi;
        }
    }
    gbar(bar, 0);

    // ======= phase 1: stable argsort-by-bin, 10 waves/bin (blocks 0..49);
    //         ygen passthrough on otherwise-idle blocks 50..249 ====================
    if (blockIdx.x < NBINS) {
        int bb = blockIdx.x;
        for (int t = tid; t < NN / 4; t += 640) ((int4*)S.p1.sBI)[t] = ((const int4*)bin_idx)[t];
        __syncthreads();
        int lane = tid & 63, w = tid >> 6;
        int start = w * 512;
        int end = (start + 512 > NN) ? NN : start + 512;
        int cnt_lt = 0, cnt_eq = 0;
        for (int base = start; base < end; base += 64) {
            int i = base + lane;
            int bi = (i < end) ? S.p1.sBI[i] : 999;
            cnt_lt += __popcll(__ballot(bi < bb));
            cnt_eq += __popcll(__ballot(bi == bb));
        }
        if (lane == 0) { S.p1.s_lt[w] = cnt_lt; S.p1.s_eq[w] = cnt_eq; }
        __syncthreads();
        int offs = 0;
        #pragma unroll
        for (int w2 = 0; w2 < 10; ++w2) {
            offs += S.p1.s_lt[w2];
            if (w2 < w) offs += S.p1.s_eq[w2];
        }
        unsigned long long below = lane ? ((~0ULL) >> (64 - lane)) : 0ULL;
        for (int base = start; base < end; base += 64) {
            int i = base + lane;
            int bi = (i < end) ? S.p1.sBI[i] : 999;
            unsigned long long m = __ballot(bi == bb);
            if (bi == bb) order[offs + __popcll(m & below)] = i;
            offs += __popcll(m);
        }
    } else {
        if (tid < 75) {
            int gI = ((int)blockIdx.x - NBINS) * 75 + tid;   // 200 blocks x 75 = 15000
            out4[15000 + gI] = (gI < 7500) ? ygen_id4[gI] : ygen4[gI - 7500];
        }
    }
    gbar(bar, 1);

    // ======= phase 2: build M (LDS-resident, no global round-trip) + conv,
    //         one block per bin, all 32 channels (blocks 0..49) ===================
    if (blockIdx.x < NBINS) {
        int p = blockIdx.x;
        if (tid < BINSZ) S.p2.s_nodes[tid] = order[p * BINSZ + tid];
        for (int t = tid; t < MROWS * BPAD / 2; t += 640) ((int*)S.p2.M)[t] = 0;
        if (tid < 384) S.p2.s_w[tid] = gcn_W[tid];           // [12][32] row-major
        __syncthreads();
        for (int t = tid; t < BINSZ * 12; t += 640) {
            int i = t / 12, k = t - i * 12;
            S.p2.s_h[t] = h[S.p2.s_nodes[i] * 12 + k];
        }
        __syncthreads();

        // local top-16 over 50 candidates (row = tid>>1, half = tid&1), packed keys
        if (tid < 200) {
            int row = tid >> 1, half = tid & 1;
            const float4* xp = (const float4*)&S.p2.s_h[row * 12];
            float4 x0 = xp[0], x1 = xp[1], x2 = xp[2];
            unsigned tv[KNN];
            #pragma unroll
            for (int k = 0; k < KNN; ++k) tv[k] = 0u;
            int j0 = half * 50;
            for (int jj = 0; jj < 50; ++jj) {
                int jn = j0 + jj;
                const float4* ap = (const float4*)&S.p2.s_h[jn * 12];
                float4 a0 = ap[0], a1 = ap[1], a2 = ap[2];
                float d = x0.x*a0.x + x0.y*a0.y + x0.z*a0.z + x0.w*a0.w
                        + x1.x*a1.x + x1.y*a1.y + x1.z*a1.z + x1.w*a1.w
                        + x2.x*a2.x + x2.y*a2.y + x2.z*a2.z + x2.w*a2.w;
                float v = 1.f / (1.f + expf(-d));
                unsigned key = (__float_as_uint(v) & 0xFFFFFF80u) | (unsigned)(127 - jn);
                if (key > tv[KNN - 1]) {
                    unsigned ins = key;
                    #pragma unroll
                    for (int k = 0; k < KNN; ++k) {
                        bool gt = ins > tv[k];
                        unsigned mx = gt ? ins : tv[k];
                        unsigned mn = gt ? tv[k] : ins;
                        tv[k] = mx; ins = mn;
                    }
                }
            }
            #pragma unroll
            for (int k = 0; k < KNN; ++k) S.p2.u.s_tv[tid * KNN + k] = tv[k];
        }
        __syncthreads();

        // merge two sorted 16-lists into M
        if (tid < BINSZ) {
            int mbase = tid * 32;
            int ia = 0, ib = 0;
            #pragma unroll
            for (int k = 0; k < KNN; ++k) {
                unsigned av = S.p2.u.s_tv[mbase + ia], bv = S.p2.u.s_tv[mbase + 16 + ib];
                bool tA = av > bv;
                unsigned key = tA ? av : bv;
                ia += tA; ib += !tA;
                int ix = 127 - (int)(key & 127u);
                S.p2.M[ix * BPAD + tid] = (_Float16)__uint_as_float(key & 0xFFFFFF80u);
            }
        }
        __syncthreads();
        if (tid < BINSZ) {
            float dsum = 1.0f;
            #pragma unroll 13
            for (int sc = 0; sc < 13; ++sc) {
                half8 m = *(const half8*)&S.p2.M[tid * BPAD + sc * 8];
                dsum += (float)m[0] + (float)m[1] + (float)m[2] + (float)m[3]
                      + (float)m[4] + (float)m[5] + (float)m[6] + (float)m[7];
            }
            S.p2.s_dis[tid] = 1.0f / sqrtf(dsum);
        }
        __syncthreads();     // s_tv dead from here; union region becomes hWd/gcn

        if (tid < 256) {     // zero pad cols 100..103 for all 32 channels
            int c = tid >> 3, r = tid & 7;
            if (r < 4) S.p2.u.c.hWd[c * BPAD + 100 + r] = 0.f;
            else       S.p2.u.c.gcn[c * BPAD + 100 + (r - 4)] = 0.f;
        }
        for (int o = tid; o < BINSZ * 32; o += 640) {
            int s = o >> 5, c = o & 31;
            float a = 0.f;
            #pragma unroll
            for (int k = 0; k < 12; ++k) a += lrelu(S.p2.s_h[s * 12 + k]) * S.p2.s_w[k * 32 + c];
            S.p2.u.c.hWd[c * BPAD + s] = S.p2.s_dis[s] * a;
        }
        __syncthreads();

        // GCN pass
        if (tid < 512) {
            int cg = tid >> 7, t1 = tid & 127, cc = t1 & 7, dg = t1 >> 3;
            int c = cg * 8 + cc;
            float acc7[7];
            #pragma unroll
            for (int r = 0; r < 7; ++r) acc7[r] = 0.f;
            for (int sc = 0; sc < 13; ++sc) {
                float4 hv0 = *(const float4*)&S.p2.u.c.hWd[c * BPAD + sc * 8];
                float4 hv1 = *(const float4*)&S.p2.u.c.hWd[c * BPAD + sc * 8 + 4];
                #pragma unroll
                for (int r = 0; r < 7; ++r) {
                    int d = dg + 16 * r;
                    half8 m = *(const half8*)&S.p2.M[d * BPAD + sc * 8];
                    acc7[r] += (float)m[0]*hv0.x + (float)m[1]*hv0.y + (float)m[2]*hv0.z + (float)m[3]*hv0.w
                             + (float)m[4]*hv1.x + (float)m[5]*hv1.y + (float)m[6]*hv1.z + (float)m[7]*hv1.w;
                }
            }
            float bc = gcn_b[c];
            #pragma unroll
            for (int r = 0; r < 7; ++r) {
                int d = dg + 16 * r;
                if (d < BINSZ) {
                    float gq = S.p2.s_dis[d] * (acc7[r] + S.p2.u.c.hWd[c * BPAD + d]) + bc;
                    S.p2.u.c.gcn[c * BPAD + d] = gq;
                    gcn_n[S.p2.s_nodes[d] * 32 + c] = gq;
                }
            }
        }
        __syncthreads();
        // GraphConv aggregate pass
        if (tid < 512) {
            int cg = tid >> 7, t1 = tid & 127, cc = t1 & 7, dg = t1 >> 3;
            int c = cg * 8 + cc;
            float acc7[7];
            #pragma unroll
            for (int r = 0; r < 7; ++r) acc7[r] = 0.f;
            for (int sc = 0; sc < 13; ++sc) {
                float4 hv0 = *(const float4*)&S.p2.u.c.gcn[c * BPAD + sc * 8];
                float4 hv1 = *(const float4*)&S.p2.u.c.gcn[c * BPAD + sc * 8 + 4];
                #pragma unroll
                for (int r = 0; r < 7; ++r) {
                    int d = dg + 16 * r;
                    half8 m = *(const half8*)&S.p2.M[d * BPAD + sc * 8];
                    acc7[r] += (float)m[0]*hv0.x + (float)m[1]*hv0.y + (float)m[2]*hv0.z + (float)m[3]*hv0.w
                             + (float)m[4]*hv1.x + (float)m[5]*hv1.y + (float)m[6]*hv1.z + (float)m[7]*hv1.w;
                }
            }
            #pragma unroll
            for (int r = 0; r < 7; ++r) {
                int d = dg + 16 * r;
                if (d < BINSZ) agg_n[S.p2.s_nodes[d] * 32 + c] = acc7[r];
            }
        }
    }
    gbar(bar, 2);

    // ================= phase 3: combine + nn2 + nn3 (all 250 blocks) =============
    {
        int n0 = blockIdx.x * NB;
        int g = tid >> 7, j = tid & 127;
        float acc[4];
        float4 r0, r1; float rt = 0.f;

        if (tid < 160) {
            float4 va = ((const float4*)(agg_n + n0 * 32))[tid];
            float4 vg = ((const float4*)(gcn_n + n0 * 32))[tid];
            int e = tid * 4, n = e / 32, k = e % 32;
            S.p3.sAG[k * NB + n] = va.x; S.p3.sAG[(k+1) * NB + n] = va.y;
            S.p3.sAG[(k+2) * NB + n] = va.z; S.p3.sAG[(k+3) * NB + n] = va.w;
            S.p3.sGC[k * NB + n] = vg.x; S.p3.sGC[(k+1) * NB + n] = vg.y;
            S.p3.sGC[(k+2) * NB + n] = vg.z; S.p3.sGC[(k+3) * NB + n] = vg.w;
        }
        if (tid >= 160 && tid < 416) ((float4*)S.p3.sW)[tid - 160] = ((const float4*)Wrel)[tid - 160];
        if (tid >= 416 && tid < 640) ((float4*)(S.p3.sW + 1024))[tid - 416] = ((const float4*)Wroot)[tid - 416];
        if (tid < 32) ((float4*)(S.p3.sW + 1024))[224 + tid] = ((const float4*)Wroot)[224 + tid];
        for (int t = tid; t < 1000; t += 640) ((float4*)(S.p3.sW + 2048))[t] = ((const float4*)A1)[t];
        __syncthreads();

        // combine: bufC[jc][n] = leaky(agg@Wrel + brel + gcn@Wroot)
        {
            int jc = tid / 20, n = tid % 20;
            float a = brel[jc];
            #pragma unroll 8
            for (int k = 0; k < 32; ++k)
                a += S.p3.sAG[k * NB + n] * S.p3.sW[k * 32 + jc] + S.p3.sGC[k * NB + n] * S.p3.sW[1024 + k * 32 + jc];
            S.p3.bufC[jc * NB + n] = lrelu(a);
        }
        __syncthreads();

        // nn2 L1: 32 -> 125
        if (j < 125) {
            float bj = ab1[j];
            acc[0] = bj; acc[1] = bj; acc[2] = bj; acc[3] = bj;
            #pragma unroll 8
            for (int k = 0; k < 32; ++k) {
                float w = S.p3.sW[2048 + k * 125 + j];
                float4 a = *(const float4*)&S.p3.bufC[k * NB + g * 4];
                acc[0] += a.x * w; acc[1] += a.y * w; acc[2] += a.z * w; acc[3] += a.w * w;
            }
            #pragma unroll
            for (int n = 0; n < 4; ++n) S.p3.bufA[j * NB + g * 4 + n] = lrelu(acc[n]);
        }
        r0 = (tid < 1000) ? ((const float4*)A2)[tid] : make_float4(0.f,0.f,0.f,0.f);
        r1 = (tid < 360)  ? ((const float4*)A2)[tid + 640] : make_float4(0.f,0.f,0.f,0.f);
        __syncthreads();
        if (tid < 1000) ((float4*)S.p3.sW)[tid] = r0;
        if (tid < 360)  ((float4*)S.p3.sW)[tid + 640] = r1;
        __syncthreads();

        // nn2 L2: 125 -> 125, chunked dbuf
        if (j < 125) { float bj = ab2[j]; acc[0] = bj; acc[1] = bj; acc[2] = bj; acc[3] = bj; }
        for (int c = 0; c < 4; ++c) {
            if (c < 3) {
                int base = (c + 1) * 1000, nf4 = (c + 1 < 3) ? 1000 : 906;
                r0 = (tid < nf4) ? ((const float4*)A2)[base + tid] : make_float4(0.f,0.f,0.f,0.f);
                r1 = (tid + 640 < nf4) ? ((const float4*)A2)[base + tid + 640] : make_float4(0.f,0.f,0.f,0.f);
                if (c + 1 == 3 && tid == 0) rt = A2[15624];
            }
            int nk = (c < 3) ? 32 : 29;
            const float* wbuf = S.p3.sW + (c & 1) * 4000;
            if (j < 125) {
                const float* arow = &S.p3.bufA[(c * 32) * NB + g * 4];
                for (int k = 0; k < nk; ++k) {
                    float w = wbuf[k * 125 + j];
                    float4 a = *(const float4*)&arow[k * NB];
                    acc[0] += a.x * w; acc[1] += a.y * w; acc[2] += a.z * w; acc[3] += a.w * w;
                }
            }
            if (c < 3) {
                float* dst = S.p3.sW + ((c + 1) & 1) * 4000;
                int nf4 = (c + 1 < 3) ? 1000 : 906;
                if (tid < nf4) ((float4*)dst)[tid] = r0;
                if (tid + 640 < nf4) ((float4*)dst)[tid + 640] = r1;
                if (c + 1 == 3 && tid == 0) dst[3624] = rt;
                __syncthreads();
            }
        }
        if (j < 125) {
            #pragma unroll
            for (int n = 0; n < 4; ++n) S.p3.bufB[j * NB + g * 4 + n] = lrelu(acc[n]);
        }
        __syncthreads();
        // stage A3 (750 floats) and B1 (4750 floats at +752)
        if (tid < 187) ((float4*)S.p3.sW)[tid] = ((const float4*)A3)[tid];
        if (tid == 187) { S.p3.sW[748] = A3[748]; S.p3.sW[749] = A3[749]; }
        for (int t = tid; t < 1187; t += 640) ((float4*)(S.p3.sW + 752))[t] = ((const float4*)B1)[t];
        if (tid == 188) { S.p3.sW[752 + 4748] = B1[4748]; S.p3.sW[752 + 4749] = B1[4749]; }
        __syncthreads();

        // nn2 L3: 125 -> 6, 4-way k-split
        if (j < 24) {
            int jj = j % 6, s = j / 6;
            int k0 = s * 32, nk = (s < 3) ? 32 : 29;
            float ps[4] = {0.f, 0.f, 0.f, 0.f};
            for (int k = 0; k < nk; ++k) {
                float w = S.p3.sW[(k0 + k) * 6 + jj];
                float4 a = *(const float4*)&S.p3.bufB[(k0 + k) * NB + g * 4];
                ps[0] += a.x * w; ps[1] += a.y * w; ps[2] += a.z * w; ps[3] += a.w * w;
            }
            #pragma unroll
            for (int n = 0; n < 4; ++n) S.p3.bufA[(s * 6 + jj) * NB + g * 4 + n] = ps[n];
        }
        __syncthreads();
        if (tid < 120) {
            int jj = tid / 20, n = tid % 20;
            float v = S.p3.bufA[jj * NB + n] + S.p3.bufA[(6 + jj) * NB + n]
                    + S.p3.bufA[(12 + jj) * NB + n] + S.p3.bufA[(18 + jj) * NB + n] + ab3[jj];
            out_ids[(n0 + n) * 6 + jj] = v;
            S.p3.bufC[(32 + jj) * NB + n] = v;
        }
        __syncthreads();

        // nn3 L1: 38 -> 125
        if (j < 125) {
            float bj = bb1[j];
            acc[0] = bj; acc[1] = bj; acc[2] = bj; acc[3] = bj;
            #pragma unroll 2
            for (int k = 0; k < 38; ++k) {
                float w = S.p3.sW[752 + k * 125 + j];
                float4 a = *(const float4*)&S.p3.bufC[k * NB + g * 4];
                acc[0] += a.x * w; acc[1] += a.y * w; acc[2] += a.z * w; acc[3] += a.w * w;
            }
            #pragma unroll
            for (int n = 0; n < 4; ++n) S.p3.bufA[j * NB + g * 4 + n] = lrelu(acc[n]);
        }
        r0 = (tid < 1000) ? ((const float4*)B2)[tid] : make_float4(0.f,0.f,0.f,0.f);
        r1 = (tid < 360)  ? ((const float4*)B2)[tid + 640] : make_float4(0.f,0.f,0.f,0.f);
        __syncthreads();
        if (tid < 1000) ((float4*)S.p3.sW)[tid] = r0;
        if (tid < 360)  ((float4*)S.p3.sW)[tid + 640] = r1;
        __syncthreads();

        // nn3 L2: 125 -> 125, chunked dbuf
        if (j < 125) { float bj = bb2[j]; acc[0] = bj; acc[1] = bj; acc[2] = bj; acc[3] = bj; }
        for (int c = 0; c < 4; ++c) {
            if (c < 3) {
                int base = (c + 1) * 1000, nf4 = (c + 1 < 3) ? 1000 : 906;
                r0 = (tid < nf4) ? ((const float4*)B2)[base + tid] : make_float4(0.f,0.f,0.f,0.f);
                r1 = (tid + 640 < nf4) ? ((const float4*)B2)[base + tid + 640] : make_float4(0.f,0.f,0.f,0.f);
                if (c + 1 == 3 && tid == 0) rt = B2[15624];
            }
            int nk = (c < 3) ? 32 : 29;
            const float* wbuf = S.p3.sW + (c & 1) * 4000;
            if (j < 125) {
                const float* arow = &S.p3.bufA[(c * 32) * NB + g * 4];
                for (int k = 0; k < nk; ++k) {
                    float w = wbuf[k * 125 + j];
                    float4 a = *(const float4*)&arow[k * NB];
                    acc[0] += a.x * w; acc[1] += a.y * w; acc[2] += a.z * w; acc[3] += a.w * w;
                }
            }
            if (c < 3) {
                float* dst = S.p3.sW + ((c + 1) & 1) * 4000;
                int nf4 = (c + 1 < 3) ? 1000 : 906;
                if (tid < nf4) ((float4*)dst)[tid] = r0;
                if (tid + 640 < nf4) ((float4*)dst)[tid + 640] = r1;
                if (c + 1 == 3 && tid == 0) dst[3624] = rt;
                __syncthreads();
            }
        }
        if (j < 125) {
            #pragma unroll
            for (int n = 0; n < 4; ++n) S.p3.bufB[j * NB + g * 4 + n] = lrelu(acc[n]);
        }
        __syncthreads();
        if (tid < 187) ((float4*)S.p3.sW)[tid] = ((const float4*)B3)[tid];
        if (tid == 187) { S.p3.sW[748] = B3[748]; S.p3.sW[749] = B3[749]; }
        __syncthreads();

        // nn3 L3: 125 -> 6, 4-way k-split
        if (j < 24) {
            int jj = j % 6, s = j / 6;
            int k0 = s * 32, nk = (s < 3) ? 32 : 29;
            float ps[4] = {0.f, 0.f, 0.f, 0.f};
            for (int k = 0; k < nk; ++k) {
                float w = S.p3.sW[(k0 + k) * 6 + jj];
                float4 a = *(const float4*)&S.p3.bufB[(k0 + k) * NB + g * 4];
                ps[0] += a.x * w; ps[1] += a.y * w; ps[2] += a.z * w; ps[3] += a.w * w;
            }
            #pragma unroll
            for (int n = 0; n < 4; ++n) S.p3.bufA[(s * 6 + jj) * NB + g * 4 + n] = ps[n];
        }
        __syncthreads();
        if (tid < 120) {
            int jj = tid / 20, n = tid % 20;
            float v = S.p3.bufA[jj * NB + n] + S.p3.bufA[(6 + jj) * NB + n]
                    + S.p3.bufA[(12 + jj) * NB + n] + S.p3.bufA[(18 + jj) * NB + n] + bb3[jj];
            out_p4[(n0 + n) * 6 + jj] = v;
        }
    }
}

extern "C" void kernel_launch(void* const* d_in, const int* in_sizes, int n_in,
                              void* d_out, int out_size, void* d_ws, size_t ws_size,
                              hipStream_t stream) {
    const float* x        = (const float*)d_in[0];
    const float* ygen_id  = (const float*)d_in[1];
    const float* ygen     = (const float*)d_in[2];
    const float* codebook = (const float*)d_in[3];
    const float* nn1_W1 = (const float*)d_in[4];  const float* nn1_b1 = (const float*)d_in[5];
    const float* nn1_W2 = (const float*)d_in[6];  const float* nn1_b2 = (const float*)d_in[7];
    const float* nn1_W3 = (const float*)d_in[8];  const float* nn1_b3 = (const float*)d_in[9];
    const float* gcn_W  = (const float*)d_in[10]; const float* gcn_b  = (const float*)d_in[11];
    const float* gc_Wrel = (const float*)d_in[12]; const float* gc_brel = (const float*)d_in[13];
    const float* gc_Wroot = (const float*)d_in[14];
    const float* nn2_W1 = (const float*)d_in[15]; const float* nn2_b1 = (const float*)d_in[16];
    const float* nn2_W2 = (const float*)d_in[17]; const float* nn2_b2 = (const float*)d_in[18];
    const float* nn2_W3 = (const float*)d_in[19]; const float* nn2_b3 = (const float*)d_in[20];
    const float* nn3_W1 = (const float*)d_in[21]; const float* nn3_b1 = (const float*)d_in[22];
    const float* nn3_W2 = (const float*)d_in[23]; const float* nn3_b2 = (const float*)d_in[24];
    const float* nn3_W3 = (const float*)d_in[25]; const float* nn3_b3 = (const float*)d_in[26];

    float* out = (float*)d_out;
    float* ws  = (float*)d_ws;

    float* h      = ws + 0;         // 60000
    float* gcn_n  = ws + 60000;     // 160000
    float* agg_n  = ws + 220000;    // 160000
    int* bin_idx  = (int*)(ws + 380000);  // 5000
    int* order    = (int*)(ws + 385000);  // 5000
    int* bar      = (int*)(ws + 390000);  // 8

    init_kernel<<<1, 64, 0, stream>>>(bar);

    fused_kernel<<<NBLK, 640, 0, stream>>>(
        x, (const float4*)ygen_id, (const float4*)ygen, codebook,
        nn1_W1, nn1_b1, nn1_W2, nn1_b2, nn1_W3, nn1_b3,
        gcn_W, gcn_b, gc_Wrel, gc_brel, gc_Wroot,
        nn2_W1, nn2_b1, nn2_W2, nn2_b2, nn2_W3, nn2_b3,
        nn3_W1, nn3_b1, nn3_W2, nn3_b2, nn3_W3, nn3_b3,
        h, gcn_n, agg_n, bin_idx, order, bar,
        out, out + 30000, (float4*)out);
}